// Round 8
// baseline (390.754 us; speedup 1.0000x reference)
//
#include <hip/hip_runtime.h>
#include <hip/hip_bf16.h>

typedef unsigned short u16;
typedef short bf16x8 __attribute__((ext_vector_type(8)));
typedef float f32x4 __attribute__((ext_vector_type(4)));

#define DM     1024
#define SEQ    4096
#define NBATCH 4
#define NWIN   31
#define NTOK   16384   // NBATCH*SEQ

__device__ __forceinline__ u16 f2b(float f) {
  union { float f; unsigned u; } x; x.f = f;
  unsigned r = (x.u + 0x7fffu + ((x.u >> 16) & 1u)) >> 16;  // RNE
  return (u16)r;
}
__device__ __forceinline__ float b2f(u16 v) {
  union { unsigned u; float f; } x; x.u = ((unsigned)v) << 16; return x.f;
}
// async global->LDS, 16B per lane. lds dest is wave-uniform base + lane*16.
__device__ __forceinline__ void gload_lds16(const u16* g, u16* l) {
  __builtin_amdgcn_global_load_lds(
      (const __attribute__((address_space(1))) void*)g,
      (__attribute__((address_space(3))) void*)l, 16, 0, 0);
}

// ---------------- fused prep: x->bf16 convert | 4x W transpose | bias concat ----------------
// flat grid partition: [0,16384) convert, [16384,20480) transpose, [20480,20492) bias.
__global__ __launch_bounds__(256) void k_prep(const float* __restrict__ x,
                                              const float* __restrict__ Wq,
                                              const float* __restrict__ Wk,
                                              const float* __restrict__ Wv,
                                              const float* __restrict__ Wo,
                                              const float* __restrict__ bq,
                                              const float* __restrict__ bk,
                                              const float* __restrict__ bv,
                                              u16* __restrict__ xb, u16* __restrict__ Wt,
                                              float* __restrict__ bcat) {
  __shared__ float tile[32][33];
  const int id = blockIdx.x, tid = threadIdx.x;
  if (id < 16384) {                     // x fp32 -> bf16, x4 vectorized
    int i = id * 256 + tid;             // n4 = NTOK*DM/4 = 4194304 = 16384*256 exactly
    float4 v = ((const float4*)x)[i];
    ushort4 o; o.x = f2b(v.x); o.y = f2b(v.y); o.z = f2b(v.z); o.w = f2b(v.w);
    ((ushort4*)xb)[i] = o;
  } else if (id < 20480) {              // W (KxN) -> Wt (NxK bf16), 32x32 tiles
    int l = id - 16384;
    int z = l >> 10, rem = l & 1023;
    const float* W = (z == 0) ? Wq : (z == 1) ? Wk : (z == 2) ? Wv : Wo;
    u16* dst = Wt + (size_t)z * DM * DM;
    int n0 = (rem & 31) * 32, k0 = (rem >> 5) * 32;
    int tx = tid & 31, ty = tid >> 5;
    #pragma unroll
    for (int i = ty; i < 32; i += 8) tile[i][tx] = W[(size_t)(k0 + i) * DM + n0 + tx];
    __syncthreads();
    #pragma unroll
    for (int i = ty; i < 32; i += 8) dst[(size_t)(n0 + i) * DM + k0 + tx] = f2b(tile[tx][i]);
  } else {                              // bias concat [bq|bk|bv]
    int i = (id - 20480) * 256 + tid;
    if (i < 3 * DM) {
      float v = (i < DM) ? bq[i] : (i < 2 * DM) ? bk[i - DM] : bv[i - 2 * DM];
      bcat[i] = v;
    }
  }
}

// ---------------- bf16 MFMA GEMM: C[M,N] = A[M,K] * Bt[N,K]^T + bias ----------------
// 128x128 tile, 4 waves each 64x64 (4x4 of 16x16x32 MFMA), BK=64.
// R4 frag pattern (HW-verified 0 bank conflicts) + launch_bounds(256,4) (R5 VALU fix).
__global__ __launch_bounds__(256, 4) void k_gemm(const u16* __restrict__ A, const u16* __restrict__ Bt,
                                                 const float* __restrict__ bias,
                                                 float* __restrict__ Cf,
                                                 u16* __restrict__ Cb, int ldc,
                                                 u16* __restrict__ Ct, int csplit,
                                                 int M, int N, int K) {
  __shared__ u16 As[128 * 64];
  __shared__ u16 Bs[128 * 64];
  const int tid = threadIdx.x;
  const int wv = tid >> 6, lane = tid & 63;
  const int quad = lane >> 4, l16 = lane & 15;
  const int lr8 = lane >> 3;                       // staging: row within 8-row issue
  const int lc8 = (((lane & 7) ^ (lr8 & 7)) * 8);  // staging: swizzled chunk
  const int m0 = blockIdx.y * 128, n0 = blockIdx.x * 128;
  const int wm = (wv >> 1) * 64, wn = (wv & 1) * 64;
  const int k7 = l16 & 7;                          // frag-read swizzle key
  f32x4 acc[4][4];
  #pragma unroll
  for (int a = 0; a < 4; ++a)
    #pragma unroll
    for (int b = 0; b < 4; ++b) acc[a][b] = (f32x4){0.f, 0.f, 0.f, 0.f};

  for (int kk = 0; kk < K; kk += 64) {
    #pragma unroll
    for (int j = 0; j < 4; ++j) {                  // A: 16 issues of 8 rows
      int e = wv * 4 + j;
      gload_lds16(A + (size_t)(m0 + e * 8 + lr8) * K + kk + lc8, As + e * 512);
    }
    #pragma unroll
    for (int j = 0; j < 4; ++j) {                  // B: 16 issues of 8 rows
      int e = wv * 4 + j;
      gload_lds16(Bt + (size_t)(n0 + e * 8 + lr8) * K + kk + lc8, Bs + e * 512);
    }
    __syncthreads();
    #pragma unroll
    for (int h = 0; h < 2; ++h) {
      bf16x8 af[4], bfr[4];
      #pragma unroll
      for (int t = 0; t < 4; ++t)
        af[t]  = *(const bf16x8*)&As[(wm + t * 16 + l16) * 64 + ((h * 4 + quad) ^ k7) * 8];
      #pragma unroll
      for (int t = 0; t < 4; ++t)
        bfr[t] = *(const bf16x8*)&Bs[(wn + t * 16 + l16) * 64 + ((h * 4 + quad) ^ k7) * 8];
      #pragma unroll
      for (int mt = 0; mt < 4; ++mt)
        #pragma unroll
        for (int nt = 0; nt < 4; ++nt)
          acc[mt][nt] = __builtin_amdgcn_mfma_f32_16x16x32_bf16(af[mt], bfr[nt], acc[mt][nt], 0, 0, 0);
    }
    __syncthreads();
  }
  #pragma unroll
  for (int mt = 0; mt < 4; ++mt) {
    #pragma unroll
    for (int nt = 0; nt < 4; ++nt) {
      int row = m0 + wm + mt * 16 + quad * 4;   // D: row=(lane>>4)*4+reg, col=lane&15
      int col = n0 + wn + nt * 16 + l16;
      float bv = bias[col];
      if (Cf) {
        #pragma unroll
        for (int r = 0; r < 4; ++r)
          Cf[(size_t)(row + r) * N + col] = acc[mt][nt][r] + bv;
      } else if (col < csplit) {
        #pragma unroll
        for (int r = 0; r < 4; ++r)
          Cb[(size_t)(row + r) * ldc + col] = f2b(acc[mt][nt][r] + bv);
      } else {
        ushort4 o;
        o.x = f2b(acc[mt][nt][0] + bv); o.y = f2b(acc[mt][nt][1] + bv);
        o.z = f2b(acc[mt][nt][2] + bv); o.w = f2b(acc[mt][nt][3] + bv);
        *(ushort4*)&Ct[(size_t)(col - csplit) * M + row] = o;
      }
    }
  }
}

// ---------------- windowed attention ----------------
// q-split 8: 32 q-rows per block, grid 1024 (992 live), XCD-swizzled so a window's
// 8 sibling blocks share an XCD L2. LDS 53 KB -> 3 blocks/CU (12 waves) for
// latency hiding of the barrier drains. No duplicated phase-1 work.
// Phase 1: S = Q*K^T/8, wave owns a 64-key slab for all 32 q, BK=64.
// Phase 2: O = P*V via Vt [d][tok]; parity-buffer stores (no atomics).
#define LDQ  2048
__global__ __launch_bounds__(256, 3) void k_attn(const u16* __restrict__ QKb, const u16* __restrict__ Vt,
                                                 u16* __restrict__ oA, u16* __restrict__ oB) {
  __shared__ u16 stage[18432];     // Qs 32x64 (4KB) + Ks 256x64 (32KB); reused as Vs 256x64 (32KB)
  __shared__ u16 Pbuf[32 * 256];   // 16KB
  __shared__ float red[2][4][32];  // 1KB: cross-wave softmax partials (max, sum)
  u16* Qs = stage;
  u16* Ks = stage + 2048;
  u16* Vs = stage;

  const int tid = threadIdx.x;
  const int wv = tid >> 6, lane = tid & 63;
  const int quad = lane >> 4, l16 = lane & 15;
  const int l7 = lane & 7, lr8 = lane >> 3;
  const int kq = (l16 & 7) + (l16 >> 3);           // frag key base (rows = 16t + l16)

  // decode swizzled flat grid: id = (pair&7) + 8*(qt + 8*(pair>>3)), pair = w + 31*b
  int id = blockIdx.x;
  int s_ = id >> 3;
  int qt = s_ & 7;
  int pair = (s_ >> 3) * 8 + (id & 7);
  if (pair >= NWIN * NBATCH) return;
  int b = pair / NWIN, w = pair - NWIN * b;

  const int s0 = w * 128;
  const size_t base2 = (size_t)b * SEQ * LDQ;
  const size_t base  = (size_t)b * SEQ * DM;
  const size_t btok  = (size_t)b * SEQ;
  const int qrow0 = s0 + qt * 32;

  f32x4 acc[2][4];   // S[q = mt*16+quad*4+r][key = wv*64 + nt*16 + l16]
  #pragma unroll
  for (int mt = 0; mt < 2; ++mt)
    #pragma unroll
    for (int nt = 0; nt < 4; ++nt) acc[mt][nt] = (f32x4){0.f, 0.f, 0.f, 0.f};

  // ---- phase 1: scores, BK=64 ----
  for (int kk = 0; kk < DM; kk += 64) {
    #pragma unroll
    for (int j = 0; j < 9; ++j) {   // 36 issues: 4 Q + 32 K
      int idx = wv * 9 + j;
      if (idx < 4) {
        int lc = (l7 ^ ((lr8 + idx) & 7)) * 8;
        gload_lds16(QKb + base2 + (size_t)(qrow0 + idx * 8 + lr8) * LDQ + kk + lc, Qs + idx * 512);
      } else {
        int f = idx - 4;
        int lc = (l7 ^ ((lr8 + f) & 7)) * 8;
        gload_lds16(QKb + DM + base2 + (size_t)(s0 + f * 8 + lr8) * LDQ + kk + lc, Ks + f * 512);
      }
    }
    __syncthreads();
    #pragma unroll
    for (int s2 = 0; s2 < 2; ++s2) {
      bf16x8 aq[2], bk[4];
      #pragma unroll
      for (int mt = 0; mt < 2; ++mt)
        aq[mt] = *(const bf16x8*)&Qs[(mt * 16 + l16) * 64 + (((s2 * 4 + quad) ^ ((kq + 2 * mt) & 7)) * 8)];
      #pragma unroll
      for (int nt = 0; nt < 4; ++nt)
        bk[nt] = *(const bf16x8*)&Ks[(wv * 64 + nt * 16 + l16) * 64 + (((s2 * 4 + quad) ^ ((kq + 2 * nt) & 7)) * 8)];
      #pragma unroll
      for (int mt = 0; mt < 2; ++mt)
        #pragma unroll
        for (int nt = 0; nt < 4; ++nt)
          acc[mt][nt] = __builtin_amdgcn_mfma_f32_16x16x32_bf16(aq[mt], bk[nt], acc[mt][nt], 0, 0, 0);
    }
    __syncthreads();
  }

  // ---- softmax over 256 keys: wave partials (64 keys) + cross-wave LDS combine ----
  float mx[2][4], sm[2][4];
  #pragma unroll
  for (int mt = 0; mt < 2; ++mt)
    #pragma unroll
    for (int r = 0; r < 4; ++r) mx[mt][r] = -1e30f;
  #pragma unroll
  for (int mt = 0; mt < 2; ++mt)
    #pragma unroll
    for (int nt = 0; nt < 4; ++nt)
      #pragma unroll
      for (int r = 0; r < 4; ++r) {
        float v = acc[mt][nt][r] * 0.125f;
        acc[mt][nt][r] = v;
        mx[mt][r] = fmaxf(mx[mt][r], v);
      }
  #pragma unroll
  for (int mt = 0; mt < 2; ++mt)
    #pragma unroll
    for (int r = 0; r < 4; ++r)
      #pragma unroll
      for (int off = 8; off > 0; off >>= 1)
        mx[mt][r] = fmaxf(mx[mt][r], __shfl_xor(mx[mt][r], off, 64));
  if (l16 == 0) {
    #pragma unroll
    for (int mt = 0; mt < 2; ++mt)
      #pragma unroll
      for (int r = 0; r < 4; ++r)
        red[0][wv][mt * 16 + quad * 4 + r] = mx[mt][r];
  }
  __syncthreads();
  float gm[2][4];
  #pragma unroll
  for (int mt = 0; mt < 2; ++mt)
    #pragma unroll
    for (int r = 0; r < 4; ++r) {
      int q = mt * 16 + quad * 4 + r;
      gm[mt][r] = fmaxf(fmaxf(red[0][0][q], red[0][1][q]), fmaxf(red[0][2][q], red[0][3][q]));
      sm[mt][r] = 0.f;
    }
  #pragma unroll
  for (int mt = 0; mt < 2; ++mt)
    #pragma unroll
    for (int nt = 0; nt < 4; ++nt)
      #pragma unroll
      for (int r = 0; r < 4; ++r) {
        float e = __expf(acc[mt][nt][r] - gm[mt][r]);
        acc[mt][nt][r] = e;
        sm[mt][r] += e;
      }
  #pragma unroll
  for (int mt = 0; mt < 2; ++mt)
    #pragma unroll
    for (int r = 0; r < 4; ++r)
      #pragma unroll
      for (int off = 8; off > 0; off >>= 1)
        sm[mt][r] += __shfl_xor(sm[mt][r], off, 64);
  if (l16 == 0) {
    #pragma unroll
    for (int mt = 0; mt < 2; ++mt)
      #pragma unroll
      for (int r = 0; r < 4; ++r)
        red[1][wv][mt * 16 + quad * 4 + r] = sm[mt][r];
  }
  __syncthreads();
  // normalize and write P (chunk-swizzled by q&7)
  #pragma unroll
  for (int mt = 0; mt < 2; ++mt)
    #pragma unroll
    for (int r = 0; r < 4; ++r) {
      int q = mt * 16 + quad * 4 + r;
      float inv = 1.f / (red[1][0][q] + red[1][1][q] + red[1][2][q] + red[1][3][q]);
      #pragma unroll
      for (int nt = 0; nt < 4; ++nt) {
        int ke = wv * 64 + nt * 16 + l16;
        int phys = (ke >> 3) ^ (q & 7);
        Pbuf[q * 256 + phys * 8 + (ke & 7)] = f2b(acc[mt][nt][r] * inv);
      }
    }
  __syncthreads();

  // ---- phase 2: O = P * V (M=32, K=256, N=1024 in 4 slabs; 64-token V steps) ----
  u16* op = ((w & 1) ? oB : oA) + base;
  for (int slab = 0; slab < 4; ++slab) {
    const int nb = slab * 256;
    f32x4 acc2[2][4];   // [mt][u]: rows q, cols nb + wv*64 + u*16 + l16
    #pragma unroll
    for (int mt = 0; mt < 2; ++mt)
      #pragma unroll
      for (int u = 0; u < 4; ++u) acc2[mt][u] = (f32x4){0.f, 0.f, 0.f, 0.f};
    for (int sk = 0; sk < 4; ++sk) {
      const int tok0 = sk * 64;
      #pragma unroll
      for (int j = 0; j < 8; ++j) {      // 32 issues: 256 d-rows x 64 tokens
        int e = wv * 8 + j;
        int lc = (l7 ^ ((lr8 + e) & 7)) * 8;
        gload_lds16(Vt + (size_t)(nb + e * 8 + lr8) * NTOK + btok + s0 + tok0 + lc, Vs + e * 512);
      }
      __syncthreads();
      #pragma unroll
      for (int s2 = 0; s2 < 2; ++s2) {
        bf16x8 af[2];
        #pragma unroll
        for (int mt = 0; mt < 2; ++mt) {
          int cP = sk * 8 + s2 * 4 + quad;             // logical chunk in 0..31
          int phys = cP ^ (l16 & 7);
          af[mt] = *(const bf16x8*)&Pbuf[(mt * 16 + l16) * 256 + phys * 8];
        }
        #pragma unroll
        for (int u = 0; u < 4; ++u) {
          bf16x8 bb = *(const bf16x8*)&Vs[(wv * 64 + u * 16 + l16) * 64 +
                                          (((s2 * 4 + quad) ^ ((kq + 2 * u) & 7)) * 8)];
          #pragma unroll
          for (int mt = 0; mt < 2; ++mt)
            acc2[mt][u] = __builtin_amdgcn_mfma_f32_16x16x32_bf16(af[mt], bb, acc2[mt][u], 0, 0, 0);
        }
      }
      __syncthreads();
    }
    #pragma unroll
    for (int mt = 0; mt < 2; ++mt)
      #pragma unroll
      for (int u = 0; u < 4; ++u) {
        int row = qrow0 + mt * 16 + quad * 4;
        int col = nb + wv * 64 + u * 16 + l16;
        #pragma unroll
        for (int r = 0; r < 4; ++r)
          op[(size_t)(row + r) * DM + col] = f2b(acc2[mt][u][r]);
      }
  }
}

// ---------------- merge parity buffers -> bf16 (x8 vectorized) ----------------
__global__ __launch_bounds__(256) void k_norm(const u16* __restrict__ oA, const u16* __restrict__ oB,
                                              u16* __restrict__ out, int n8) {
  int i = blockIdx.x * 256 + threadIdx.x;
  if (i >= n8) return;
  int s = (i >> 7) & (SEQ - 1);     // 128 groups of 8 per token row
  uint4 a = ((const uint4*)oA)[i];
  uint4 r = a;
  if (s >= 128 && s < 3968) {       // interior: one even + one odd window
    uint4 bq = ((const uint4*)oB)[i];
    const unsigned* ap = (const unsigned*)&a;
    const unsigned* bp = (const unsigned*)&bq;
    unsigned* rp = (unsigned*)&r;
    #pragma unroll
    for (int k = 0; k < 4; ++k) {
      float lo = 0.5f * (b2f((u16)(ap[k] & 0xffff)) + b2f((u16)(bp[k] & 0xffff)));
      float hi = 0.5f * (b2f((u16)(ap[k] >> 16))    + b2f((u16)(bp[k] >> 16)));
      rp[k] = (unsigned)f2b(lo) | ((unsigned)f2b(hi) << 16);
    }
  }
  ((uint4*)out)[i] = r;
}

extern "C" void kernel_launch(void* const* d_in, const int* in_sizes, int n_in,
                              void* d_out, int out_size, void* d_ws, size_t ws_size,
                              hipStream_t stream) {
  const float* x  = (const float*)d_in[0];
  const float* Wq = (const float*)d_in[1];
  const float* bq = (const float*)d_in[2];
  const float* Wk = (const float*)d_in[3];
  const float* bk = (const float*)d_in[4];
  const float* Wv = (const float*)d_in[5];
  const float* bv = (const float*)d_in[6];
  const float* Wo = (const float*)d_in[7];
  const float* bo = (const float*)d_in[8];
  float* out = (float*)d_out;

  char* ws = (char*)d_ws;
  const size_t MB = 1024 * 1024;
  u16*   xb   = (u16*)(ws);                 // 32 MB: x bf16; later merged attn output
  u16*   qkb  = (u16*)(ws + 32 * MB);       // 64 MB: [tok][2048] q|k
  u16*   vtb  = (u16*)(ws + 96 * MB);       // 32 MB: V transposed [d][tok]
  u16*   wqt  = (u16*)(ws + 128 * MB);      // 8 MB: wqt|wkt|wvt|wot contiguous
  float* bcat = (float*)(ws + 136 * MB);    // 12 KB
  u16*   oA   = (u16*)(ws + 137 * MB);      // 32 MB
  u16*   oB   = (u16*)(ws + 169 * MB);      // 32 MB  (end: 201 MB)

  // fused prep: convert (16384 blocks) + 4 transposes (4096) + bias concat (12)
  k_prep<<<20492, 256, 0, stream>>>(x, Wq, Wk, Wv, Wo, bq, bk, bv, xb, wqt, bcat);

  // fused QKV GEMM: N=3072 over [wqt|wkt|wvt]; q,k -> qkb row-major; v -> vtb transposed
  k_gemm<<<dim3(3 * DM / 128, NTOK / 128), 256, 0, stream>>>(
      xb, wqt, bcat, nullptr, qkb, 2048, vtb, 2048, NTOK, 3 * DM, DM);

  k_attn<<<1024, 256, 0, stream>>>(qkb, vtb, oA, oB);

  int n8tok = (int)((size_t)NTOK * DM / 8);
  k_norm<<<(n8tok + 255) / 256, 256, 0, stream>>>(oA, oB, xb, n8tok);

  u16* wot = wqt + 3 * (size_t)DM * DM;
  k_gemm<<<dim3(DM / 128, NTOK / 128), 256, 0, stream>>>(
      xb, wot, bo, out, nullptr, DM, nullptr, DM, NTOK, DM, DM);
}